// Round 1
// baseline (802.714 us; speedup 1.0000x reference)
//
#include <hip/hip_runtime.h>
#include <math.h>

#define N_NODES 50000
#define N_EDGES 800000
#define D 64

__device__ __forceinline__ float selu_f(float x) {
    const float scale = 1.0507009873554805f;
    const float alpha = 1.6732632423543772f;
    return x > 0.0f ? scale * x : scale * alpha * expm1f(x);
}

// h[n][o] = sum_k feat[n][k] * W[o][k]
__global__ __launch_bounds__(256) void gemm_kernel(const float* __restrict__ feat,
                                                   const float* __restrict__ W,
                                                   float* __restrict__ h) {
    // Wt[k][o] = W[o][k], padded to kill bank conflicts on the k-major read
    __shared__ float Wt[D][D + 1];
    const int tid = threadIdx.x;
    for (int i = tid; i < D * D; i += 256) {
        int o = i >> 6;
        int d = i & 63;
        Wt[d][o] = W[i];
    }
    __syncthreads();

    const int row = blockIdx.x * 4 + (tid >> 6);
    const int col = tid & 63;
    if (row >= N_NODES) return;

    const float* frow = feat + (size_t)row * D;
    float acc = 0.0f;
#pragma unroll
    for (int k = 0; k < D; ++k) {
        acc += frow[k] * Wt[k][col];
    }
    h[(size_t)row * D + col] = acc;
}

// agg[dst] += h[src] * w   (16 threads per edge, float4 per thread)
__global__ __launch_bounds__(256) void scatter_kernel(const float* __restrict__ h,
                                                      const float* __restrict__ ew,
                                                      const int* __restrict__ esrc,
                                                      const int* __restrict__ edst,
                                                      float* __restrict__ agg) {
    const long long idx = (long long)blockIdx.x * 256 + threadIdx.x;
    const int e = (int)(idx >> 4);
    if (e >= N_EDGES) return;
    const int j = (int)(idx & 15);

    const int src = esrc[e];
    const int dst = edst[e];
    const float w = ew[e];

    const float4 hv = *(const float4*)(h + (size_t)src * D + j * 4);
    float* ap = agg + (size_t)dst * D + j * 4;
    atomicAdd(ap + 0, hv.x * w);
    atomicAdd(ap + 1, hv.y * w);
    atomicAdd(ap + 2, hv.z * w);
    atomicAdd(ap + 3, hv.w * w);
}

// out = selu(h * skip_weight + agg + bias), float4 per thread
__global__ __launch_bounds__(256) void epilogue_kernel(const float* __restrict__ h,
                                                       const float* __restrict__ agg,
                                                       const float* __restrict__ bias,
                                                       const float* __restrict__ skipw,
                                                       float* __restrict__ out) {
    const int idx = blockIdx.x * 256 + threadIdx.x;
    if (idx >= N_NODES * D / 4) return;

    const float4 hv = ((const float4*)h)[idx];
    const float4 av = ((const float4*)agg)[idx];
    const int col = (idx & 15) * 4;

    float4 o;
    o.x = selu_f(hv.x * skipw[col + 0] + av.x + bias[col + 0]);
    o.y = selu_f(hv.y * skipw[col + 1] + av.y + bias[col + 1]);
    o.z = selu_f(hv.z * skipw[col + 2] + av.z + bias[col + 2]);
    o.w = selu_f(hv.w * skipw[col + 3] + av.w + bias[col + 3]);
    ((float4*)out)[idx] = o;
}

extern "C" void kernel_launch(void* const* d_in, const int* in_sizes, int n_in,
                              void* d_out, int out_size, void* d_ws, size_t ws_size,
                              hipStream_t stream) {
    const float* feat  = (const float*)d_in[0];
    const float* W     = (const float*)d_in[1];
    const float* bias  = (const float*)d_in[2];
    const float* skipw = (const float*)d_in[3];
    const float* ew    = (const float*)d_in[4];
    const int*   esrc  = (const int*)d_in[5];
    const int*   edst  = (const int*)d_in[6];
    float* out = (float*)d_out;

    float* h   = (float*)d_ws;
    float* agg = h + (size_t)N_NODES * D;

    // agg must start at zero (d_ws is poisoned to 0xAA before every call)
    hipMemsetAsync(agg, 0, (size_t)N_NODES * D * sizeof(float), stream);

    // 1) h = X @ W^T  (4 rows per block)
    gemm_kernel<<<(N_NODES + 3) / 4, 256, 0, stream>>>(feat, W, h);

    // 2) agg[dst] += h[src] * w  (16 threads/edge)
    scatter_kernel<<<(N_EDGES * 16 + 255) / 256, 256, 0, stream>>>(h, ew, esrc, edst, agg);

    // 3) out = selu(h*skip + agg + bias)
    epilogue_kernel<<<(N_NODES * D / 4 + 255) / 256, 256, 0, stream>>>(h, agg, bias, skipw, out);
}

// Round 2
// 363.049 us; speedup vs baseline: 2.2110x; 2.2110x over previous
//
#include <hip/hip_runtime.h>
#include <math.h>

#define N_NODES 50000
#define N_EDGES 800000
#define D 64

__device__ __forceinline__ float selu_f(float x) {
    const float scale = 1.0507009873554805f;
    const float alpha = 1.6732632423543772f;
    return x > 0.0f ? scale * x : scale * alpha * expm1f(x);
}

// h[n][o] = sum_k feat[n][k] * W[o][k]
__global__ __launch_bounds__(256) void gemm_kernel(const float* __restrict__ feat,
                                                   const float* __restrict__ W,
                                                   float* __restrict__ h) {
    __shared__ float Wt[D][D + 1];
    const int tid = threadIdx.x;
    for (int i = tid; i < D * D; i += 256) {
        int o = i >> 6;
        int d = i & 63;
        Wt[d][o] = W[i];
    }
    __syncthreads();

    const int row = blockIdx.x * 4 + (tid >> 6);
    const int col = tid & 63;
    if (row >= N_NODES) return;

    const float* frow = feat + (size_t)row * D;
    float acc = 0.0f;
#pragma unroll
    for (int k = 0; k < D; ++k) {
        acc += frow[k] * Wt[k][col];
    }
    h[(size_t)row * D + col] = acc;
}

// counts[dst]++ over all edges
__global__ __launch_bounds__(256) void hist_kernel(const int* __restrict__ edst,
                                                   int* __restrict__ counts) {
    const int e = blockIdx.x * 256 + threadIdx.x;
    if (e < N_EDGES) atomicAdd(&counts[edst[e]], 1);
}

// Single-block exclusive scan of counts -> offsets (and a second copy: cursor)
__global__ __launch_bounds__(1024) void scan_kernel(const int* __restrict__ counts,
                                                    int* __restrict__ offsets,
                                                    int* __restrict__ cursor) {
    const int T = 1024;
    const int CH = (N_NODES + T - 1) / T;  // 49
    const int tid = threadIdx.x;
    const int beg = tid * CH;
    const int end = min(beg + CH, N_NODES);

    int sum = 0;
    for (int i = beg; i < end; ++i) sum += counts[i];

    __shared__ int s[T];
    s[tid] = sum;
    __syncthreads();
    // Hillis-Steele inclusive scan
    for (int off = 1; off < T; off <<= 1) {
        int v = (tid >= off) ? s[tid - off] : 0;
        __syncthreads();
        s[tid] += v;
        __syncthreads();
    }
    int run = (tid == 0) ? 0 : s[tid - 1];  // exclusive prefix of this chunk

    for (int i = beg; i < end; ++i) {
        offsets[i] = run;
        cursor[i] = run;
        run += counts[i];
    }
    if (tid == T - 1) offsets[N_NODES] = run;  // total = N_EDGES
}

// Scatter edges into dst-sorted buckets
__global__ __launch_bounds__(256) void bucket_kernel(const int* __restrict__ esrc,
                                                     const int* __restrict__ edst,
                                                     const float* __restrict__ ew,
                                                     int* __restrict__ cursor,
                                                     int* __restrict__ sorted_src,
                                                     float* __restrict__ sorted_w) {
    const int e = blockIdx.x * 256 + threadIdx.x;
    if (e >= N_EDGES) return;
    const int dst = edst[e];
    const int pos = atomicAdd(&cursor[dst], 1);
    sorted_src[pos] = esrc[e];
    sorted_w[pos] = ew[e];
}

// One wave per dst node, lane = output dim. Segmented reduction + fused epilogue.
__global__ __launch_bounds__(256) void agg_epilogue_kernel(const float* __restrict__ h,
                                                           const int* __restrict__ offsets,
                                                           const int* __restrict__ sorted_src,
                                                           const float* __restrict__ sorted_w,
                                                           const float* __restrict__ bias,
                                                           const float* __restrict__ skipw,
                                                           float* __restrict__ out) {
    const int gtid = blockIdx.x * 256 + threadIdx.x;
    const int n = gtid >> 6;      // node = wave index
    const int lane = gtid & 63;   // output dim
    if (n >= N_NODES) return;

    const int beg = offsets[n];
    const int end = offsets[n + 1];

    float acc = 0.0f;
    for (int i = beg; i < end; i += 64) {
        const int cnt = min(64, end - i);
        int s = 0;
        float wv = 0.0f;
        if (lane < cnt) {
            s = sorted_src[i + lane];
            wv = sorted_w[i + lane];
        }
        for (int j = 0; j < cnt; ++j) {
            const int sj = __shfl(s, j);
            const float wj = __shfl(wv, j);
            acc += h[(size_t)sj * D + lane] * wj;
        }
    }

    const float skip = h[(size_t)n * D + lane] * skipw[lane];
    out[(size_t)n * D + lane] = selu_f(skip + acc + bias[lane]);
}

extern "C" void kernel_launch(void* const* d_in, const int* in_sizes, int n_in,
                              void* d_out, int out_size, void* d_ws, size_t ws_size,
                              hipStream_t stream) {
    const float* feat  = (const float*)d_in[0];
    const float* W     = (const float*)d_in[1];
    const float* bias  = (const float*)d_in[2];
    const float* skipw = (const float*)d_in[3];
    const float* ew    = (const float*)d_in[4];
    const int*   esrc  = (const int*)d_in[5];
    const int*   edst  = (const int*)d_in[6];
    float* out = (float*)d_out;

    // workspace layout (4-byte units)
    float* h          = (float*)d_ws;                       // N_NODES*D
    int*   counts     = (int*)(h + (size_t)N_NODES * D);    // N_NODES
    int*   offsets    = counts + N_NODES;                   // N_NODES+1
    int*   cursor     = offsets + N_NODES + 1;              // N_NODES
    int*   sorted_src = cursor + N_NODES;                   // N_EDGES
    float* sorted_w   = (float*)(sorted_src + N_EDGES);     // N_EDGES

    // counts must start at zero (ws is poisoned each call)
    hipMemsetAsync(counts, 0, (size_t)N_NODES * sizeof(int), stream);

    // 1) h = X @ W^T
    gemm_kernel<<<(N_NODES + 3) / 4, 256, 0, stream>>>(feat, W, h);

    // 2) counting sort of edges by dst
    hist_kernel<<<(N_EDGES + 255) / 256, 256, 0, stream>>>(edst, counts);
    scan_kernel<<<1, 1024, 0, stream>>>(counts, offsets, cursor);
    bucket_kernel<<<(N_EDGES + 255) / 256, 256, 0, stream>>>(esrc, edst, ew, cursor,
                                                             sorted_src, sorted_w);

    // 3) segmented reduction + fused skip/bias/SELU epilogue
    agg_epilogue_kernel<<<(N_NODES * 64 + 255) / 256, 256, 0, stream>>>(
        h, offsets, sorted_src, sorted_w, bias, skipw, out);
}

// Round 3
// 265.681 us; speedup vs baseline: 3.0213x; 1.3665x over previous
//
#include <hip/hip_runtime.h>
#include <math.h>

#define N_NODES 50000
#define N_EDGES 800000
#define D 64
#define NB 196  // (N_NODES + 255) / 256

__device__ __forceinline__ float selu_f(float x) {
    const float scale = 1.0507009873554805f;
    const float alpha = 1.6732632423543772f;
    return x > 0.0f ? scale * x : scale * alpha * expm1f(x);
}

// h[n][o] = sum_k feat[n][k] * W[o][k]
__global__ __launch_bounds__(256) void gemm_kernel(const float* __restrict__ feat,
                                                   const float* __restrict__ W,
                                                   float* __restrict__ h) {
    __shared__ float Wt[D][D + 1];
    const int tid = threadIdx.x;
    for (int i = tid; i < D * D; i += 256) {
        int o = i >> 6;
        int d = i & 63;
        Wt[d][o] = W[i];
    }
    __syncthreads();

    const int row = blockIdx.x * 4 + (tid >> 6);
    const int col = tid & 63;
    if (row >= N_NODES) return;

    const float* frow = feat + (size_t)row * D;
    float acc = 0.0f;
#pragma unroll
    for (int k = 0; k < D; ++k) {
        acc += frow[k] * Wt[k][col];
    }
    h[(size_t)row * D + col] = acc;
}

// counts[dst]++ over all edges
__global__ __launch_bounds__(256) void hist_kernel(const int* __restrict__ edst,
                                                   int* __restrict__ counts) {
    const int e = blockIdx.x * 256 + threadIdx.x;
    if (e < N_EDGES) atomicAdd(&counts[edst[e]], 1);
}

// blocksum[b] = sum of counts[b*256 .. b*256+255]
__global__ __launch_bounds__(256) void scan_partial(const int* __restrict__ counts,
                                                    int* __restrict__ blocksum) {
    __shared__ int s[256];
    const int tid = threadIdx.x;
    const int i = blockIdx.x * 256 + tid;
    s[tid] = (i < N_NODES) ? counts[i] : 0;
    __syncthreads();
    for (int off = 128; off > 0; off >>= 1) {
        if (tid < off) s[tid] += s[tid + off];
        __syncthreads();
    }
    if (tid == 0) blocksum[blockIdx.x] = s[0];
}

// exclusive scan of NB block sums -> blockoff; also write offsets[N_NODES]
__global__ __launch_bounds__(256) void scan_blocksums(const int* __restrict__ blocksum,
                                                      int* __restrict__ blockoff,
                                                      int* __restrict__ offsets) {
    __shared__ int s[256];
    const int tid = threadIdx.x;
    const int v = (tid < NB) ? blocksum[tid] : 0;
    s[tid] = v;
    __syncthreads();
    for (int off = 1; off < 256; off <<= 1) {
        int t = (tid >= off) ? s[tid - off] : 0;
        __syncthreads();
        s[tid] += t;
        __syncthreads();
    }
    if (tid < NB) blockoff[tid] = s[tid] - v;  // exclusive prefix
    if (tid == 0) offsets[N_NODES] = N_EDGES;
}

// per-block exclusive scan of counts + block offset -> offsets, cursor
__global__ __launch_bounds__(256) void scan_final(const int* __restrict__ counts,
                                                  const int* __restrict__ blockoff,
                                                  int* __restrict__ offsets,
                                                  int* __restrict__ cursor) {
    __shared__ int s[256];
    const int tid = threadIdx.x;
    const int i = blockIdx.x * 256 + tid;
    const int v = (i < N_NODES) ? counts[i] : 0;
    s[tid] = v;
    __syncthreads();
    for (int off = 1; off < 256; off <<= 1) {
        int t = (tid >= off) ? s[tid - off] : 0;
        __syncthreads();
        s[tid] += t;
        __syncthreads();
    }
    const int excl = s[tid] - v + blockoff[blockIdx.x];
    if (i < N_NODES) {
        offsets[i] = excl;
        cursor[i] = excl;
    }
}

// Scatter edges into dst-sorted buckets
__global__ __launch_bounds__(256) void bucket_kernel(const int* __restrict__ esrc,
                                                     const int* __restrict__ edst,
                                                     const float* __restrict__ ew,
                                                     int* __restrict__ cursor,
                                                     int* __restrict__ sorted_src,
                                                     float* __restrict__ sorted_w) {
    const int e = blockIdx.x * 256 + threadIdx.x;
    if (e >= N_EDGES) return;
    const int dst = edst[e];
    const int pos = atomicAdd(&cursor[dst], 1);
    sorted_src[pos] = esrc[e];
    sorted_w[pos] = ew[e];
}

// One wave per dst node, lane = output dim. Segmented reduction + fused epilogue.
__global__ __launch_bounds__(256) void agg_epilogue_kernel(const float* __restrict__ h,
                                                           const int* __restrict__ offsets,
                                                           const int* __restrict__ sorted_src,
                                                           const float* __restrict__ sorted_w,
                                                           const float* __restrict__ bias,
                                                           const float* __restrict__ skipw,
                                                           float* __restrict__ out) {
    const int gtid = blockIdx.x * 256 + threadIdx.x;
    const int n = gtid >> 6;      // node = wave index
    const int lane = gtid & 63;   // output dim
    if (n >= N_NODES) return;

    const int beg = offsets[n];
    const int end = offsets[n + 1];

    float acc = 0.0f;
    for (int i = beg; i < end; i += 64) {
        const int cnt = min(64, end - i);
        int s = 0;
        float wv = 0.0f;
        if (lane < cnt) {
            s = sorted_src[i + lane];
            wv = sorted_w[i + lane];
        }
        for (int j = 0; j < cnt; ++j) {
            const int sj = __shfl(s, j);
            const float wj = __shfl(wv, j);
            acc += h[(size_t)sj * D + lane] * wj;
        }
    }

    const float skip = h[(size_t)n * D + lane] * skipw[lane];
    out[(size_t)n * D + lane] = selu_f(skip + acc + bias[lane]);
}

extern "C" void kernel_launch(void* const* d_in, const int* in_sizes, int n_in,
                              void* d_out, int out_size, void* d_ws, size_t ws_size,
                              hipStream_t stream) {
    const float* feat  = (const float*)d_in[0];
    const float* W     = (const float*)d_in[1];
    const float* bias  = (const float*)d_in[2];
    const float* skipw = (const float*)d_in[3];
    const float* ew    = (const float*)d_in[4];
    const int*   esrc  = (const int*)d_in[5];
    const int*   edst  = (const int*)d_in[6];
    float* out = (float*)d_out;

    // workspace layout (4-byte units)
    float* h          = (float*)d_ws;                       // N_NODES*D
    int*   counts     = (int*)(h + (size_t)N_NODES * D);    // N_NODES
    int*   offsets    = counts + N_NODES;                   // N_NODES+1
    int*   cursor     = offsets + N_NODES + 1;              // N_NODES
    int*   sorted_src = cursor + N_NODES;                   // N_EDGES
    float* sorted_w   = (float*)(sorted_src + N_EDGES);     // N_EDGES
    int*   blocksum   = (int*)(sorted_w + N_EDGES);         // NB
    int*   blockoff   = blocksum + NB;                      // NB

    // counts must start at zero (ws is poisoned each call)
    hipMemsetAsync(counts, 0, (size_t)N_NODES * sizeof(int), stream);

    // 1) h = X @ W^T
    gemm_kernel<<<(N_NODES + 3) / 4, 256, 0, stream>>>(feat, W, h);

    // 2) counting sort of edges by dst (hist + 3-stage scan + bucket)
    hist_kernel<<<(N_EDGES + 255) / 256, 256, 0, stream>>>(edst, counts);
    scan_partial<<<NB, 256, 0, stream>>>(counts, blocksum);
    scan_blocksums<<<1, 256, 0, stream>>>(blocksum, blockoff, offsets);
    scan_final<<<NB, 256, 0, stream>>>(counts, blockoff, offsets, cursor);
    bucket_kernel<<<(N_EDGES + 255) / 256, 256, 0, stream>>>(esrc, edst, ew, cursor,
                                                             sorted_src, sorted_w);

    // 3) segmented reduction + fused skip/bias/SELU epilogue
    agg_epilogue_kernel<<<(N_NODES * 64 + 255) / 256, 256, 0, stream>>>(
        h, offsets, sorted_src, sorted_w, bias, skipw, out);
}

// Round 4
// 243.721 us; speedup vs baseline: 3.2936x; 1.0901x over previous
//
#include <hip/hip_runtime.h>
#include <math.h>

#define N_NODES 50000
#define N_EDGES 800000
#define D 64

__device__ __forceinline__ float selu_f(float x) {
    const float scale = 1.0507009873554805f;
    const float alpha = 1.6732632423543772f;
    return x > 0.0f ? scale * x : scale * alpha * expm1f(x);
}

// h[n][o] = sum_k feat[n][k] * W[o][k]
__global__ __launch_bounds__(256) void gemm_kernel(const float* __restrict__ feat,
                                                   const float* __restrict__ W,
                                                   float* __restrict__ h) {
    __shared__ float Wt[D][D + 1];
    const int tid = threadIdx.x;
    for (int i = tid; i < D * D; i += 256) {
        int o = i >> 6;
        int d = i & 63;
        Wt[d][o] = W[i];
    }
    __syncthreads();

    const int row = blockIdx.x * 4 + (tid >> 6);
    const int col = tid & 63;
    if (row >= N_NODES) return;

    const float* frow = feat + (size_t)row * D;
    float acc = 0.0f;
#pragma unroll
    for (int k = 0; k < D; ++k) {
        acc += frow[k] * Wt[k][col];
    }
    h[(size_t)row * D + col] = acc;
}

// Build per-dst linked lists: next[e] = old head[dst], head[dst] = e.
// next[] writes are coalesced (indexed by e); only head[] sees random atomics.
__global__ __launch_bounds__(256) void link_kernel(const int* __restrict__ edst,
                                                   int* __restrict__ head,
                                                   int* __restrict__ next) {
    const int e = blockIdx.x * 256 + threadIdx.x;
    if (e >= N_EDGES) return;
    const int dst = edst[e];
    next[e] = atomicExch(&head[dst], e);
}

// One wave per dst node, lane = output dim. Walk the linked list, accumulate,
// fused skip/bias/SELU epilogue.
__global__ __launch_bounds__(256) void agg_epilogue_kernel(const float* __restrict__ h,
                                                           const int* __restrict__ head,
                                                           const int* __restrict__ next,
                                                           const int* __restrict__ esrc,
                                                           const float* __restrict__ ew,
                                                           const float* __restrict__ bias,
                                                           const float* __restrict__ skipw,
                                                           float* __restrict__ out) {
    const int gtid = blockIdx.x * 256 + threadIdx.x;
    const int n = gtid >> 6;      // node = wave index
    const int lane = gtid & 63;   // output dim
    if (n >= N_NODES) return;

    float acc = 0.0f;
    int e = head[n];  // wave-uniform
    while (e != -1) {
        const int src = esrc[e];   // uniform load
        const float w = ew[e];     // uniform load
        const int en = next[e];    // uniform load — the only serial dependency
        acc += h[(size_t)src * D + lane] * w;  // coalesced 256B row gather
        e = en;
    }

    const float skip = h[(size_t)n * D + lane] * skipw[lane];
    out[(size_t)n * D + lane] = selu_f(skip + acc + bias[lane]);
}

extern "C" void kernel_launch(void* const* d_in, const int* in_sizes, int n_in,
                              void* d_out, int out_size, void* d_ws, size_t ws_size,
                              hipStream_t stream) {
    const float* feat  = (const float*)d_in[0];
    const float* W     = (const float*)d_in[1];
    const float* bias  = (const float*)d_in[2];
    const float* skipw = (const float*)d_in[3];
    const float* ew    = (const float*)d_in[4];
    const int*   esrc  = (const int*)d_in[5];
    const int*   edst  = (const int*)d_in[6];
    float* out = (float*)d_out;

    // workspace layout (4-byte units)
    float* h    = (float*)d_ws;                    // N_NODES*D
    int*   head = (int*)(h + (size_t)N_NODES * D); // N_NODES
    int*   next = head + N_NODES;                  // N_EDGES

    // head must start at -1 (ws is poisoned each call); 0xFF bytes == -1
    hipMemsetAsync(head, 0xFF, (size_t)N_NODES * sizeof(int), stream);

    // 1) h = X @ W^T
    gemm_kernel<<<(N_NODES + 3) / 4, 256, 0, stream>>>(feat, W, h);

    // 2) per-dst linked lists
    link_kernel<<<(N_EDGES + 255) / 256, 256, 0, stream>>>(edst, head, next);

    // 3) segmented reduction via list walk + fused skip/bias/SELU epilogue
    agg_epilogue_kernel<<<(N_NODES * 64 + 255) / 256, 256, 0, stream>>>(
        h, head, next, esrc, ew, bias, skipw, out);
}